// Round 7
// baseline (121.484 us; speedup 1.0000x reference)
//
#include <hip/hip_runtime.h>
#include <hip/hip_bf16.h>

#define IS 256
#define NEARV 0.1f
#define FARV 100.0f
#define NTX 16                     // 16x16 tiles of 16x16 px
#define NTILES 256
#define FPB 64                     // faces per binning block (all in wave 0)
#define SEGCAP 64                  // max entries per (block,tile) segment == FPB
#define TILECAP 8192               // 128 segments * 64 -> pow2 addressing
#define CHK 32                     // entries per raster chunk (2 chunks/segment)
#define RBLOCKS 2048
#define RWAVES (RBLOCKS * 4)       // 8192 waves, 8 item-slots each
#define NSLOTS (NTILES * 256)      // 65536 static item slots

// ---------------- kernel 1: fused prep + bin ----------------
// Grid: 256 blocks x 256 threads.
//  - every thread clears one z-buffer pixel (d_out used directly as raw float
//    bits; positive floats compare as uints, so uint atomicMin == float min)
//  - blocks b < nb additionally own faces [b*64, b*64+64): wave 0 gathers,
//    transforms (arithmetic identical to rounds 1-6, all absmax 0.0), culls,
//    writes the 3-float4 face record, and scatters the face index into its
//    PRIVATE per-(block,tile) list segment via LDS cursors. cnt2[b*256+t] is
//    written unconditionally -> no global atomics, no pre-zeroing, and the
//    dispatch boundary orders everything for the raster.
// Face record float4s: [x0,y0,x1,y1] [x2,y2,inv_area,iz0] [iz1,iz2,_,_]
__global__ void kprepbin(const float* __restrict__ verts, const int* __restrict__ faces,
                         float4* __restrict__ fd, unsigned int* __restrict__ zb,
                         int* __restrict__ cnt2, unsigned short* __restrict__ list,
                         int nf, int nb) {
    const int tid = threadIdx.x;
    const int b = blockIdx.x;
    zb[b * 256 + tid] = 0x42C80000u;  // __float_as_uint(100.0f); grid covers IS*IS exactly

    if (b >= nb) return;  // block-uniform: no barrier divergence

    __shared__ int scnt[NTILES];
    scnt[tid] = 0;
    __syncthreads();

    const int f = b * FPB + tid;  // only wave 0 (tid < 64) carries faces
    if (tid < FPB && f < nf) {
        int i0 = faces[f * 3 + 0];
        int i1 = faces[f * 3 + 1];
        int i2 = faces[f * 3 + 2];
        // transform (v - eye; R == I exactly in fp32 for this camera)
        float z0 = verts[i0 * 3 + 2] + 2.7320508075688772f;
        float z1 = verts[i1 * 3 + 2] + 2.7320508075688772f;
        float z2 = verts[i2 * 3 + 2] + 2.7320508075688772f;
        bool front = (z0 > NEARV) && (z1 > NEARV) && (z2 > NEARV);
        float zs0 = (fabsf(z0) < 1e-5f) ? 1e-5f : z0;
        float zs1 = (fabsf(z1) < 1e-5f) ? 1e-5f : z1;
        float zs2 = (fabsf(z2) < 1e-5f) ? 1e-5f : z2;
        float d0 = zs0 * 0.57735026918962576f;  // zs * tan(30 deg)
        float d1 = zs1 * 0.57735026918962576f;
        float d2 = zs2 * 0.57735026918962576f;
        float x0 = verts[i0 * 3 + 0] / d0;
        float y0 = verts[i0 * 3 + 1] / d0;
        float x1 = verts[i1 * 3 + 0] / d1;
        float y1 = verts[i1 * 3 + 1] / d1;
        float x2 = verts[i2 * 3 + 0] / d2;
        float y2 = verts[i2 * 3 + 1] / d2;
        float area = (x1 - x0) * (y2 - y0) - (x2 - x0) * (y1 - y0);
        if (front && (fabsf(area) > 1e-8f)) {
            float xmin = fminf(x0, fminf(x1, x2));
            float xmax = fmaxf(x0, fmaxf(x1, x2));
            float ymin = fminf(y0, fminf(y1, y2));
            float ymax = fmaxf(y0, fmaxf(y1, y2));
            float ia = 1.0f / area;  // |area| > 1e-8 so area_s == area
            float iz0 = 1.0f / fmaxf(z0, 1e-4f);
            float iz1 = 1.0f / fmaxf(z1, 1e-4f);
            float iz2 = 1.0f / fmaxf(z2, 1e-4f);
            float4* o = fd + (size_t)f * 4;
            o[0] = make_float4(x0, y0, x1, y1);
            o[1] = make_float4(x2, y2, ia, iz0);
            o[2] = make_float4(iz1, iz2, 0.0f, 0.0f);
            // conservative float tile range, exact predicate re-tested inside
            // (same dyadic constants as rounds 1-6 -> bit-identical face sets)
            float tminx = fminf(fmaxf((xmin * 256.0f + 225.0f) * (1.0f / 32.0f), -2.0f), 17.0f);
            float tmaxx = fminf(fmaxf((xmax * 256.0f + 255.0f) * (1.0f / 32.0f), -2.0f), 17.0f);
            float tminy = fminf(fmaxf((ymin * 256.0f + 225.0f) * (1.0f / 32.0f), -2.0f), 17.0f);
            float tmaxy = fminf(fmaxf((ymax * 256.0f + 255.0f) * (1.0f / 32.0f), -2.0f), 17.0f);
            int kx0 = max(0, (int)ceilf(tminx) - 1);
            int kx1 = min(NTX - 1, (int)floorf(tmaxx) + 1);
            int ky0 = max(0, (int)ceilf(tminy) - 1);
            int ky1 = min(NTX - 1, (int)floorf(tmaxy) + 1);
            for (int ky = ky0; ky <= ky1; ++ky) {
                float py_lo = (float)(32 * ky - 255) * (1.0f / 256.0f);
                float py_hi = (float)(32 * ky - 225) * (1.0f / 256.0f);
                if (!(ymin <= py_hi && ymax >= py_lo)) continue;
                for (int kx = kx0; kx <= kx1; ++kx) {
                    float px_lo = (float)(32 * kx - 255) * (1.0f / 256.0f);
                    float px_hi = (float)(32 * kx - 225) * (1.0f / 256.0f);
                    if (xmin <= px_hi && xmax >= px_lo) {
                        int t = ky * NTX + kx;
                        int slot = atomicAdd(&scnt[t], 1);  // LDS, wave-0 only
                        list[(size_t)t * TILECAP + b * SEGCAP + slot] = (unsigned short)f;
                    }
                }
            }
        }
    }
    __syncthreads();
    cnt2[b * NTILES + tid] = scnt[tid];  // unconditional: raster needs no zeroed memory
}

// ---------------- kernel 2: raster ----------------
// Static item grid, one wave per slot visit: slot s of tile t -> segment
// b = s>>1, chunk c = s&1 of the private (b,t) list. Wave w = u*256+s handles
// slot s of tiles {u + 32k}: a hot tile's 256 slots land on 256 DISTINCT
// waves -> balanced with zero scheduling machinery. Empty slots cost one
// compare (b >= nb) or one uniform cnt2 load. Per entry: 1 uniform ushort +
// 3 uniform float4 L1 loads, ~95 VALU of 4-way-ILP pixel math
// (expression-identical to rounds 1-6). One atomicMin per covered pixel.
__launch_bounds__(256)
__global__ void kraster(const float4* __restrict__ fd, const unsigned short* __restrict__ list,
                        const int* __restrict__ cnt2, unsigned int* __restrict__ zb, int nb) {
    const int wid = blockIdx.x * 4 + (threadIdx.x >> 6);
    const int lane = threadIdx.x & 63;
    const int cx = lane & 15;
    const int ry = lane >> 4;

    for (int it = wid; it < NSLOTS; it += RWAVES) {
        const int tile = it >> 8;
        const int slot = it & 255;
        const int b = slot >> 1;
        const int c = slot & 1;
        if (b >= nb) continue;                        // free skip (no memory access)
        const int cnt = cnt2[b * NTILES + tile];
        const int n = min(CHK, cnt - c * CHK);
        if (n <= 0) continue;

        const int bx = tile & 15;
        const int by = tile >> 4;
        const int j = bx * 16 + cx;
        // pixel centers: (2*idx + 1 - 256)/256 (exact in fp32)
        const float px = ((float)(2 * j + 1) - 256.0f) * (1.0f / 256.0f);
        float py[4];
        int row[4];
#pragma unroll
        for (int r = 0; r < 4; ++r) {
            row[r] = by * 16 + ry + 4 * r;
            py[r] = ((float)(2 * row[r] + 1) - 256.0f) * (1.0f / 256.0f);
        }
        const unsigned short* lp = list + (size_t)tile * TILECAP + b * SEGCAP + c * CHK;

        float mx[4] = {0.0f, 0.0f, 0.0f, 0.0f};

#pragma unroll 2
        for (int e = 0; e < n; ++e) {
            const int fidx = lp[e];                   // uniform -> one L1 line
            const float4* p = fd + (size_t)fidx * 4;
            float4 a0 = p[0];
            float4 a1 = p[1];
            float4 a2 = p[2];
            float dx0 = a0.x - px, dx1 = a0.z - px, dx2 = a1.x - px;
#pragma unroll
            for (int r = 0; r < 4; ++r) {
                float dy0 = a0.y - py[r], dy1 = a0.w - py[r], dy2 = a1.y - py[r];
                float e0 = dx1 * dy2 - dx2 * dy1;
                float e1 = dx2 * dy0 - dx0 * dy2;
                float w0 = e0 * a1.z;
                float w1 = e1 * a1.z;
                float w2 = 1.0f - w0 - w1;
                float invz = w0 * a1.w + w1 * a2.x + w2 * a2.y;
                float invzc = fmaxf(invz, 1e-6f);
                // zp = 1/invzc; valid iff inside && NEAR < zp < FAR <=> 0.01 < invzc < 10
                bool ok = (w0 >= 0.0f) && (w1 >= 0.0f) && (w2 >= 0.0f) &&
                          (invzc < 10.0f) && (invzc > 0.01f);
                if (ok) mx[r] = fmaxf(mx[r], invzc);
            }
        }
#pragma unroll
        for (int r = 0; r < 4; ++r) {
            if (mx[r] > 0.0f) {
                float zp = 1.0f / mx[r];  // correctly-rounded 1/x is monotone => min-exact
                atomicMin(&zb[row[r] * IS + j], __float_as_uint(zp));
            }
        }
    }
}

extern "C" void kernel_launch(void* const* d_in, const int* in_sizes, int n_in,
                              void* d_out, int out_size, void* d_ws, size_t ws_size,
                              hipStream_t stream) {
    const float* verts = (const float*)d_in[0];
    const int* faces = (const int*)d_in[1];
    unsigned int* zb = (unsigned int*)d_out;  // float bits, min'd in place

    const int nf = in_sizes[1] / 3;           // 5000 (< 65536: ushort indices ok)
    const int nb = (nf + FPB - 1) / FPB;      // 79 binning blocks (<= 128 for TILECAP)

    char* ws = (char*)d_ws;
    size_t off = 0;
    float4* fd = (float4*)(ws + off);         off += (size_t)nf * 64;            // 320 KB
    off = (off + 255) & ~(size_t)255;
    int* cnt2 = (int*)(ws + off);             off += (size_t)nb * NTILES * 4;    // 81 KB
    off = (off + 255) & ~(size_t)255;
    unsigned short* list = (unsigned short*)(ws + off);  // 256*8192*2 = 4 MB

    kprepbin<<<(IS * IS) / 256, 256, 0, stream>>>(verts, faces, fd, zb, cnt2, list, nf, nb);
    kraster<<<RBLOCKS, 256, 0, stream>>>(fd, list, cnt2, zb, nb);
}